// Round 3
// baseline (2940.918 us; speedup 1.0000x reference)
//
#include <hip/hip_runtime.h>

#define BB 32
#define TT 256
#define INP 64
#define EE 128
#define DD 128
#define OO 32

// ---- workspace layout (float offsets) ----
// ENCWH aliases XWF; EPT/ENCWLH alias XWB (stream-ordered: xw -> lstm consumes XW,
// then proj writes EPT/ENCWH/ENCWLH, then decoder reads them).
#define OFF_XWF    0u          // B*T*512 staging (xw -> lstm)
#define OFF_ENCWH  0u          // B*128*512 half2-as-float (proj -> decoder)
#define OFF_XWB    4194304u    // B*T*512 staging
#define OFF_EPT    4194304u    // B*256*128 fp32, t-major, pre-scaled by 2*log2e
#define OFF_ENCWLH 5242880u    // B*128*32 half2-as-float
#define OFF_HF     8388608u    // B*T*128
#define OFF_HBR    9437184u    // B*T*128
#define OFF_ZC     10485760u   // B*512
#define OFF_WHHTF  10502144u   // 512*128 packed [k4][j][4]
#define OFF_WHHTB  10567680u
#define OFF_WIHTF  10633216u   // 512*64  packed [i4][j][4]
#define OFF_WIHTB  10665984u
#define OFF_WHHDT  10698752u   // 512*128 packed [k4][j][4]
#define OFF_WCAT   10764288u   // 256*672 packed [k4][j][4]
#define OFF_WLHT   10936320u   // 128*32 packed [k4][m][4] fp32
#define OFF_WAHH   10940416u   // 128*64 half2 [d][k2]
#define OFF_WYH    10948608u   // 16*512 half2 [m2][j]

typedef _Float16 h2_t __attribute__((ext_vector_type(2)));
typedef _Float16 half8_t __attribute__((ext_vector_type(8)));
typedef float f32x4_t __attribute__((ext_vector_type(4)));

__device__ __forceinline__ float fexp2(float x){ return __builtin_amdgcn_exp2f(x); }
__device__ __forceinline__ float frcp(float x){ return __builtin_amdgcn_rcpf(x); }
__device__ __forceinline__ float fsig(float x){ return frcp(1.0f + fexp2(-1.4426950408889634f * x)); }
__device__ __forceinline__ float ftanh_(float x){ return 1.0f - 2.0f * frcp(1.0f + fexp2(2.8853900817779268f * x)); }
__device__ __forceinline__ float packh2(float a, float b){
  h2_t t; t.x = (_Float16)a; t.y = (_Float16)b; return __builtin_bit_cast(float, t);
}
__device__ __forceinline__ h2_t ash2(float f){ return __builtin_bit_cast(h2_t, f); }
__device__ __forceinline__ float fdot2_(float a, float b, float c){
  return __builtin_amdgcn_fdot2(ash2(a), ash2(b), c, false);
}

#define C2F 2.8853900817779268f
#define L2E 1.4426950408889634f

// X-macro repeaters: arrays of persistent operands MUST be named SSA values.
// An alloca (even statically indexed) needs promote-alloca to become registers,
// and that pass's size budget is derived from the default 4-waves/EU occupancy
// target (128 VGPRs) -- a 144-dword aggregate stays in scratch regardless of
// __launch_bounds__ (R1/R2 evidence: VGPR pinned at 128, WRITE_SIZE 2.8x).
#define REP4(M)  M(0) M(1) M(2) M(3)
#define REP9(M)  M(0) M(1) M(2) M(3) M(4) M(5) M(6) M(7) M(8)
#define REP16(M) M(0) M(1) M(2) M(3) M(4) M(5) M(6) M(7) M(8) M(9) M(10) M(11) M(12) M(13) M(14) M(15)
#define REP32(M) M(0) M(1) M(2) M(3) M(4) M(5) M(6) M(7) M(8) M(9) M(10) M(11) M(12) M(13) M(14) M(15) \
                 M(16) M(17) M(18) M(19) M(20) M(21) M(22) M(23) M(24) M(25) M(26) M(27) M(28) M(29) M(30) M(31)

// ---------------- K0a: weight transposes / packing ----------------
__global__ void pack_kernel(const float* __restrict__ Whh_f, const float* __restrict__ Whh_b,
                            const float* __restrict__ Wih_f, const float* __restrict__ Wih_b,
                            const float* __restrict__ Whh_d, const float* __restrict__ Wa,
                            const float* __restrict__ Wih_d, const float* __restrict__ Wl,
                            float* __restrict__ ws){
  unsigned e = blockIdx.x * 256u + threadIdx.x;
  if (e < 65536u){ unsigned j=e>>7, k=e&127u; ws[OFF_WHHTF + (k>>2)*2048u + j*4u + (k&3u)] = Whh_f[e]; return; }
  e -= 65536u;
  if (e < 65536u){ unsigned j=e>>7, k=e&127u; ws[OFF_WHHTB + (k>>2)*2048u + j*4u + (k&3u)] = Whh_b[e]; return; }
  e -= 65536u;
  if (e < 32768u){ unsigned j=e>>6, i=e&63u; ws[OFF_WIHTF + (i>>2)*2048u + j*4u + (i&3u)] = Wih_f[e]; return; }
  e -= 32768u;
  if (e < 32768u){ unsigned j=e>>6, i=e&63u; ws[OFF_WIHTB + (i>>2)*2048u + j*4u + (i&3u)] = Wih_b[e]; return; }
  e -= 32768u;
  if (e < 65536u){ unsigned j=e>>7, k=e&127u; ws[OFF_WHHDT + (k>>2)*2048u + j*4u + (k&3u)] = Whh_d[e]; return; }
  e -= 65536u;
  if (e < 172032u){
    unsigned j = e >> 8, k = e & 255u;  // j<672, k<256
    float val;
    if (j < 128u)      val = Wa[j*384u + 128u + k];
    else if (j < 640u) val = Wih_d[(j-128u)*288u + 32u + k];
    else               val = Wl[(j-640u)*384u + 128u + k];
    ws[OFF_WCAT + (k>>2)*2688u + j*4u + (k&3u)] = val; return;
  }
  e -= 172032u;
  if (e < 4096u){ unsigned k=e>>5, m=e&31u; ws[OFF_WLHT + (k>>2)*128u + m*4u + (k&3u)] = Wl[m*384u + k]; return; }
  e -= 4096u;
  if (e < 8192u){ // WAHH [d][k2] fp16 pairs over k
    unsigned d = e >> 6, k2 = e & 63u;
    ws[OFF_WAHH + e] = packh2(Wa[d*384u + 2u*k2], Wa[d*384u + 2u*k2 + 1u]); return;
  }
  e -= 8192u;
  if (e < 8192u){ // WYH [m2][j] fp16 pairs over m (first 32 cols of Wih_d)
    unsigned m2 = e >> 9, j = e & 511u;
    ws[OFF_WYH + e] = packh2(Wih_d[j*288u + 2u*m2], Wih_d[j*288u + 2u*m2 + 1u]); return;
  }
}

// ---------------- K0b: zc[b][j] = b_d[j] + dec_h0[b] @ Whh_d[j,:] ----------------
__global__ __launch_bounds__(512) void zc_kernel(const float* __restrict__ dec_h0,
                                                 const float* __restrict__ b_d,
                                                 float* __restrict__ ws){
  __shared__ __align__(16) float h0[128];
  int b = blockIdx.x, j = threadIdx.x;
  if (j < 128) h0[j] = dec_h0[b*128 + j];
  __syncthreads();
  const float* WT = ws + OFF_WHHDT;
  float4 a4 = make_float4(0.f,0.f,0.f,0.f);
  #pragma unroll
  for (int k4 = 0; k4 < 32; k4++){
    float4 wv = *(const float4*)(WT + k4*2048 + j*4);
    float4 hv = *(const float4*)(h0 + k4*4);
    a4.x += wv.x*hv.x; a4.y += wv.y*hv.y; a4.z += wv.z*hv.z; a4.w += wv.w*hv.w;
  }
  ws[OFF_ZC + b*512 + j] = b_d[j] + (a4.x + a4.y) + (a4.z + a4.w);
}

// ---------------- K1: xW staging ----------------
__global__ __launch_bounds__(512) void xw_kernel(const float* __restrict__ x,
                                                 const int* __restrict__ lengths,
                                                 const float* __restrict__ b_f,
                                                 const float* __restrict__ b_b,
                                                 float* __restrict__ ws){
  int bx = blockIdx.x;
  int dir = bx >> 9, b = (bx >> 4) & 31, tile = bx & 15;
  int t0 = tile * 16;
  int len = lengths[b];
  __shared__ __align__(16) float xrow[16][64];
  const float* WT   = ws + (dir ? OFF_WIHTB : OFF_WIHTF);
  const float* bias = dir ? b_b : b_f;
  float* out = ws + (dir ? OFF_XWB : OFF_XWF) + (unsigned)b * TT * 512;
  int tid = threadIdx.x;
  for (int idx = tid; idx < 1024; idx += 512){
    int r = idx >> 6, i = idx & 63;
    int s = t0 + r;
    int src = dir ? ((s < len) ? (len - 1 - s) : 0) : s;
    xrow[r][i] = x[((unsigned)b * TT + src) * 64 + i];
  }
  __syncthreads();
  int j = tid;
  float bj = bias[j];
  float acc[16];
  #pragma unroll
  for (int r = 0; r < 16; r++) acc[r] = bj;
  #pragma unroll 4
  for (int i4 = 0; i4 < 16; i4++){
    float4 wv = *(const float4*)(WT + i4*2048 + j*4);
    #pragma unroll
    for (int r = 0; r < 16; r++){
      float4 xv = *(const float4*)(&xrow[r][i4*4]);
      acc[r] += wv.x*xv.x + wv.y*xv.y + wv.z*xv.z + wv.w*xv.w;
    }
  }
  #pragma unroll
  for (int r = 0; r < 16; r++) out[(t0 + r)*512 + j] = acc[r];
}

// ---------------- K2: LSTM recurrence ----------------
// Whh row held in 32 NAMED float4 SSA values (not an alloca) so it stays in
// VGPRs; amdgpu_waves_per_eu(2,2) sets the occupancy/pressure target to the
// 256-VGPR budget (64 blocks on 256 CUs -> 1 block/CU, no occupancy cost).
__global__ __launch_bounds__(512) __attribute__((amdgpu_waves_per_eu(2, 2)))
void lstm_kernel(const int* __restrict__ lengths,
                 float* __restrict__ ws){
  int bx = blockIdx.x;
  int b = bx & 31, dir = bx >> 5;
  int len = lengths[b];
  if (len < 1) len = 1; if (len > TT) len = TT;
  const float* xW = ws + (dir ? OFF_XWB : OFF_XWF) + (unsigned)b * TT * 512;
  const float* WT = ws + (dir ? OFF_WHHTB : OFF_WHHTF);
  float* hout = ws + (dir ? OFF_HBR : OFF_HF) + (unsigned)b * TT * 128;
  __shared__ __align__(16) float hsh[128];
  __shared__ __align__(16) float csh[128];
  __shared__ __align__(16) float zsh[512];
  int j = threadIdx.x;
#define DECLW(i) float4 w##i;
  REP32(DECLW)
#undef DECLW
#define LDW(i) w##i = *(const float4*)(WT + (i)*2048 + j*4);
  REP32(LDW)
#undef LDW
  if (j < 128){ hsh[j] = 0.f; csh[j] = 0.f; }
  for (int t = 0; t < len; t++){
    __syncthreads();
    float4 a4 = make_float4(xW[t*512 + j], 0.f, 0.f, 0.f);
#define ACCW(i) { float4 hv = *(const float4*)(hsh + (i)*4); \
    a4.x = fmaf(w##i.x, hv.x, a4.x); a4.y = fmaf(w##i.y, hv.y, a4.y); \
    a4.z = fmaf(w##i.z, hv.z, a4.z); a4.w = fmaf(w##i.w, hv.w, a4.w); }
    REP32(ACCW)
#undef ACCW
    zsh[j] = (a4.x + a4.y) + (a4.z + a4.w);
    __syncthreads();
    if (j < 128){
      float zi = zsh[j], zf = zsh[128+j], zg = zsh[256+j], zo = zsh[384+j];
      float c = fsig(zf)*csh[j] + fsig(zi)*ftanh_(zg);
      float h = fsig(zo)*ftanh_(c);
      csh[j] = c; hsh[j] = h;
      hout[t*128 + j] = h;
    }
  }
}

// ---------------- K3: enc projections -> EPT (t-major fp32), ENCWH/ENCWLH (fp16 pairs) ----------------
__global__ __launch_bounds__(192) void proj_kernel(const int* __restrict__ lengths,
                                                   const float* __restrict__ ba,
                                                   float* __restrict__ ws){
  int bx = blockIdx.x;
  int b = bx >> 4, tile = bx & 15;
  int len = lengths[b];
  if (len < 1) len = 1; if (len > TT) len = TT;
  int t0 = tile * 16;
  __shared__ __align__(16) float enc[16][256];
  int tid = threadIdx.x;
  const float* hf  = ws + OFF_HF  + (unsigned)b * TT * 128;
  const float* hbr = ws + OFF_HBR + (unsigned)b * TT * 128;
  for (int idx = tid; idx < 4096; idx += 192){
    int r = idx >> 8, k = idx & 255;
    int t = t0 + r;
    float vv = 0.f;
    if (t < len) vv = (k < 128) ? hf[t*128 + k] : hbr[(len-1-t)*128 + (k-128)];
    enc[r][k] = vv;
  }
  __syncthreads();
  if (tid >= 168) return;
  int j0 = tid * 4;
  float acc[16][4];
  #pragma unroll
  for (int r = 0; r < 16; r++){ acc[r][0]=0.f; acc[r][1]=0.f; acc[r][2]=0.f; acc[r][3]=0.f; }
  const float* WC = ws + OFF_WCAT;
  for (int k4 = 0; k4 < 64; k4++){
    float4 w0 = *(const float4*)(WC + k4*2688 + (j0+0)*4);
    float4 w1 = *(const float4*)(WC + k4*2688 + (j0+1)*4);
    float4 w2 = *(const float4*)(WC + k4*2688 + (j0+2)*4);
    float4 w3 = *(const float4*)(WC + k4*2688 + (j0+3)*4);
    #pragma unroll
    for (int r = 0; r < 16; r++){
      float4 ev = *(const float4*)(&enc[r][k4*4]);
      acc[r][0] += w0.x*ev.x + w0.y*ev.y + w0.z*ev.z + w0.w*ev.w;
      acc[r][1] += w1.x*ev.x + w1.y*ev.y + w1.z*ev.z + w1.w*ev.w;
      acc[r][2] += w2.x*ev.x + w2.y*ev.y + w2.z*ev.z + w2.w*ev.w;
      acc[r][3] += w3.x*ev.x + w3.y*ev.y + w3.z*ev.z + w3.w*ev.w;
    }
  }
  float* epo  = ws + OFF_EPT    + (unsigned)b * TT * 128;   // [t][d]
  float* eWh  = ws + OFF_ENCWH  + (unsigned)b * 128 * 512;  // [t2][j] half2
  float* eWlh = ws + OFF_ENCWLH + (unsigned)b * 128 * 32;   // [t2][m] half2
  #pragma unroll
  for (int c = 0; c < 4; c++){
    int j = j0 + c;
    if (j < 128){
      float bj = ba[j];
      for (int r = 0; r < 16; r++) epo[(t0 + r)*128 + j] = (acc[r][c] + bj) * C2F;
    } else if (j < 640){
      for (int r2 = 0; r2 < 8; r2++)
        eWh[(tile*8 + r2)*512 + (j - 128)] = packh2(acc[2*r2][c], acc[2*r2+1][c]);
    } else {
      for (int r2 = 0; r2 < 8; r2++)
        eWlh[(tile*8 + r2)*32 + (j - 640)] = packh2(acc[2*r2][c], acc[2*r2+1][c]);
    }
  }
}

// ---------------- K4: attention decoder ----------------
// MFMA edition, named-register build: all persistent operands (36 B-fragments,
// 4 Wa_h fragments, zc, v) are individual SSA variables so they can never fall
// into scratch via a failed alloca promotion. amdgpu_waves_per_eu(2,2) gives
// the allocator the full 256-VGPR/wave budget (32 blocks -> 1 per CU max).
__global__ __launch_bounds__(512) __attribute__((amdgpu_waves_per_eu(2, 2)))
void decoder_kernel(const int* __restrict__ lengths,
                    const float* __restrict__ dec_h0,
                    const float* __restrict__ dec_c0,
                    const float* __restrict__ v,
                    const float* __restrict__ bl,
                    float* __restrict__ ws,
                    float* __restrict__ out){
  __shared__ __align__(16) float ep_lds[32768];   // [t][d] linear, fp32
  __shared__ __align__(16) float pool[4096];      // partial / zsh / red (disjoint live ranges)
  __shared__ __align__(16) float qsh[128];        // C2F * q_d
  __shared__ __align__(16) float au_h2[144];      // half2 pairs: a over t [0..127], y over m [128..143]
  __shared__ __align__(16) float hsh[128];
  __shared__ __align__(16) float c0sh[128];
  __shared__ __align__(16) float h_h2[64];        // half2 pairs of h over k
  __shared__ __align__(16) float ylds[32];
  __shared__ float mlsw[8];                       // per-wave {max, sum} pairs

  int b = blockIdx.x;
  int len = lengths[b];
  if (len < 1) len = 1; if (len > TT) len = TT;
  int tid = threadIdx.x;
  int lane = tid & 63, w = tid >> 6;
  int rg = lane >> 4, c16 = lane & 15;
  int rg4 = rg * 4;
  int dg = tid & 31, tg = tid >> 5;
  int dg4 = dg * 4;

  const float* EPT  = ws + OFF_EPT    + (unsigned)b * 32768;
  const float* EWH  = ws + OFF_ENCWH  + (unsigned)b * 65536;
  const float* EWLH = ws + OFF_ENCWLH + (unsigned)b * 4096;
  const float* WLHT = ws + OFF_WLHT;
  float* outp = out + (unsigned)b * 8223;

  // ---- persistent B fragments for Phase D: [encW(256); Wy(32)] f16, 64 cols per wave ----
  // layout per MFMA 16x16x32: lane holds B[k = ks*32 + (lane>>4)*8 + c][col = w*64+nt*16+(lane&15)]
  half8_t bf0_0, bf0_1, bf0_2, bf0_3, bf0_4, bf0_5, bf0_6, bf0_7, bf0_8;
  half8_t bf1_0, bf1_1, bf1_2, bf1_3, bf1_4, bf1_5, bf1_6, bf1_7, bf1_8;
  half8_t bf2_0, bf2_1, bf2_2, bf2_3, bf2_4, bf2_5, bf2_6, bf2_7, bf2_8;
  half8_t bf3_0, bf3_1, bf3_2, bf3_3, bf3_4, bf3_5, bf3_6, bf3_7, bf3_8;
  int j0_ = w*64 + 0*16 + c16;
  int j1_ = w*64 + 1*16 + c16;
  int j2_ = w*64 + 2*16 + c16;
  int j3_ = w*64 + 3*16 + c16;
#define LDBF(nt, ks) { float4 t_; \
    t_.x = EWH[((ks)*16 + rg4 + 0)*512 + j##nt##_]; \
    t_.y = EWH[((ks)*16 + rg4 + 1)*512 + j##nt##_]; \
    t_.z = EWH[((ks)*16 + rg4 + 2)*512 + j##nt##_]; \
    t_.w = EWH[((ks)*16 + rg4 + 3)*512 + j##nt##_]; \
    bf##nt##_##ks = __builtin_bit_cast(half8_t, t_); }
#define LDBF0(ks) LDBF(0, ks)
#define LDBF1(ks) LDBF(1, ks)
#define LDBF2(ks) LDBF(2, ks)
#define LDBF3(ks) LDBF(3, ks)
  REP9(LDBF0) REP9(LDBF1) REP9(LDBF2) REP9(LDBF3)
#undef LDBF0
#undef LDBF1
#undef LDBF2
#undef LDBF3
#undef LDBF
  // ks = 8 slot is Wy (overwrite what LDBF read out of range? no -- ks goes 0..8,
  // ks==8 read EWH rows 128..131 which do not exist; overwrite with WYH):
  {
#define LDBY(nt) { float4 t_; \
    t_.x = ws[OFF_WYH + (rg4 + 0)*512 + j##nt##_]; \
    t_.y = ws[OFF_WYH + (rg4 + 1)*512 + j##nt##_]; \
    t_.z = ws[OFF_WYH + (rg4 + 2)*512 + j##nt##_]; \
    t_.w = ws[OFF_WYH + (rg4 + 3)*512 + j##nt##_]; \
    bf##nt##_8 = __builtin_bit_cast(half8_t, t_); }
    LDBY(0) LDBY(1) LDBY(2) LDBY(3)
#undef LDBY
  }
  // ---- persistent B fragments for Phase A: Wa_h f16, 16 q-outputs per wave ----
  half8_t wa0, wa1, wa2, wa3;
  {
    int dq = w*16 + c16;
#define LDWA(ks) { float4 t_; \
    t_.x = ws[OFF_WAHH + dq*64 + (ks)*16 + rg4 + 0]; \
    t_.y = ws[OFF_WAHH + dq*64 + (ks)*16 + rg4 + 1]; \
    t_.z = ws[OFF_WAHH + dq*64 + (ks)*16 + rg4 + 2]; \
    t_.w = ws[OFF_WAHH + dq*64 + (ks)*16 + rg4 + 3]; \
    wa##ks = __builtin_bit_cast(half8_t, t_); }
    REP4(LDWA)
#undef LDWA
  }
  float zc_0 = ws[OFF_ZC + b*512 + w*64 +  0 + c16];
  float zc_1 = ws[OFF_ZC + b*512 + w*64 + 16 + c16];
  float zc_2 = ws[OFF_ZC + b*512 + w*64 + 32 + c16];
  float zc_3 = ws[OFF_ZC + b*512 + w*64 + 48 + c16];
  float vx = v[dg4 + 0], vy = v[dg4 + 1], vz = v[dg4 + 2], vw = v[dg4 + 3];

  // ---- ep -> LDS (linear, vectorized) ----
  {
    const float4* src = (const float4*)EPT;
    float4* dst = (float4*)ep_lds;
    #pragma unroll
    for (int c = 0; c < 16; c++) dst[c*512 + tid] = src[c*512 + tid];
  }
  if (tid < 128){
    hsh[tid]  = dec_h0[b*128 + tid];
    c0sh[tid] = dec_c0[b*128 + tid];
  }
  if (tid < 64) h_h2[tid] = packh2(dec_h0[b*128 + 2*tid], dec_h0[b*128 + 2*tid + 1]);
  if (tid < 32) ylds[tid] = 0.f;
  if (tid < 31) outp[tid] = 0.f;

  for (int t = 0; t < TT; t++){
    __syncthreads();                               // (1) ylds/h_h2 ready
    if (tid < 16) au_h2[128 + tid] = packh2(ylds[2*tid], ylds[2*tid+1]);
    // ---- Phase A: q = Wa_h.h via MFMA (A rows replicated with h) ----
    {
      f32x4_t qa = {0.f, 0.f, 0.f, 0.f};
#define MFA(ks) { float4 hf4_ = *(const float4*)(h_h2 + (ks)*16 + rg4); \
      qa = __builtin_amdgcn_mfma_f32_16x16x32_f16(__builtin_bit_cast(half8_t, hf4_), wa##ks, qa, 0, 0, 0); }
      REP4(MFA)
#undef MFA
      if (rg == 0) qsh[w*16 + c16] = qa[0] * C2F;
    }
    __syncthreads();                               // (2) qsh ready
    // ---- Phase B: per-thread 4d x 16t sigmoid-dot partials (named p0..p15) ----
    {
      float4 q4 = *(const float4*)(qsh + dg4);
      int t0 = tg * 16;
#define PBC(k) float p##k = 0.f; \
      if (t0 + (k) < len){ \
        float4 e4_ = *(const float4*)(ep_lds + (t0 + (k))*128 + dg4); \
        p##k =      vx * frcp(1.f + fexp2(e4_.x + q4.x)); \
        p##k = fmaf(vy, frcp(1.f + fexp2(e4_.y + q4.y)), p##k); \
        p##k = fmaf(vz, frcp(1.f + fexp2(e4_.z + q4.z)), p##k); \
        p##k = fmaf(vw, frcp(1.f + fexp2(e4_.w + q4.w)), p##k); \
      } \
      p##k += __shfl_xor(p##k, 16);
      REP16(PBC)
#undef PBC
      if (dg < 16){
#define STP(k) pool[dg*256 + ((t0 + (k) + dg) & 255)] = p##k;
        REP16(STP)
#undef STP
      }
    }
    __syncthreads();                               // (3) partials ready
    // ---- Phase C: softmax (one cross-wave exchange) ----
    float e = 0.f, mm = -1e30f;
    if (tid < 256){
      float s = -1e30f;
      if (tid < len){
        float ps = 0.f;
        #pragma unroll
        for (int dgi = 0; dgi < 16; dgi++)
          ps += pool[dgi*256 + ((tid + dgi) & 255)];
        s = ps * (-2.f * L2E);                     // vsum constant cancels in softmax
      }
      mm = s;
      #pragma unroll
      for (int off = 32; off; off >>= 1) mm = fmaxf(mm, __shfl_xor(mm, off));
      if (tid < len) e = fexp2(s - mm);
      float ss = e;
      #pragma unroll
      for (int off = 32; off; off >>= 1) ss += __shfl_xor(ss, off);
      if ((tid & 63) == 0){ mlsw[(tid>>6)*2] = mm; mlsw[(tid>>6)*2 + 1] = ss; }
    }
    __syncthreads();                               // (4) wave max/sum ready
    if (tid < 256){
      float gm = fmaxf(fmaxf(mlsw[0], mlsw[2]), fmaxf(mlsw[4], mlsw[6]));
      float tot = mlsw[1]*fexp2(mlsw[0] - gm) + mlsw[3]*fexp2(mlsw[2] - gm)
                + mlsw[5]*fexp2(mlsw[4] - gm) + mlsw[7]*fexp2(mlsw[6] - gm);
      float scale = fexp2(mm - gm) * frcp(tot);
      float e1 = __shfl_xor(e, 1);
      if (!(tid & 1)) au_h2[tid >> 1] = packh2(e*scale, e1*scale);
    }
    __syncthreads();                               // (5) a ready
    // ---- Phase D: z = zc + [a;y].[encW;Wy] via MFMA (A rows replicated) ----
    {
      f32x4_t a0 = {zc_0, zc_0, zc_0, zc_0};
      f32x4_t a1 = {zc_1, zc_1, zc_1, zc_1};
      f32x4_t a2 = {zc_2, zc_2, zc_2, zc_2};
      f32x4_t a3 = {zc_3, zc_3, zc_3, zc_3};
#define MFD(ks) { float4 af_ = *(const float4*)(au_h2 + (ks)*16 + rg4); \
      half8_t a8_ = __builtin_bit_cast(half8_t, af_); \
      a0 = __builtin_amdgcn_mfma_f32_16x16x32_f16(a8_, bf0_##ks, a0, 0, 0, 0); \
      a1 = __builtin_amdgcn_mfma_f32_16x16x32_f16(a8_, bf1_##ks, a1, 0, 0, 0); \
      a2 = __builtin_amdgcn_mfma_f32_16x16x32_f16(a8_, bf2_##ks, a2, 0, 0, 0); \
      a3 = __builtin_amdgcn_mfma_f32_16x16x32_f16(a8_, bf3_##ks, a3, 0, 0, 0); }
      REP9(MFD)
#undef MFD
      float zv = (rg == 0) ? a0[0] : (rg == 1) ? a1[0] : (rg == 2) ? a2[0] : a3[0];
      pool[tid] = zv;                              // zsh alias; j == tid mapping preserved
    }
    __syncthreads();                               // (6) z ready
    // ---- Phase E: gates (c0 constant per reference) ----
    if (tid < 128){
      float zi = pool[tid], zf = pool[128+tid], zg = pool[256+tid], zo = pool[384+tid];
      float c = fsig(zf)*c0sh[tid] + fsig(zi)*ftanh_(zg);
      hsh[tid] = fsig(zo)*ftanh_(c);
    }
    __syncthreads();                               // (7) h ready
    // pack h to half2 (idle lanes), in parallel with Phase F
    if (tid >= 256 && tid < 320){
      int i = tid - 256;
      h_h2[i] = packh2(hsh[2*i], hsh[2*i+1]);
    }
    // ---- Phase F: y = a.eWl + h.Wl_h + bl ----
    if (tid < 256){
      int m = tid & 31, pp = tid >> 5;
      float acc = 0.f;
      #pragma unroll
      for (int ri = 0; ri < 16; ri++){
        int r = pp + ri*8;
        acc = fdot2_(au_h2[r], EWLH[r*32 + m], acc);
      }
      #pragma unroll
      for (int k4 = pp; k4 < 32; k4 += 8){
        float4 hv = *(const float4*)(hsh + k4*4);
        float4 wv = *(const float4*)(WLHT + k4*128 + m*4);
        acc += hv.x*wv.x + hv.y*wv.y + hv.z*wv.z + hv.w*wv.w;
      }
      pool[tid] = acc;                             // red alias (256 entries)
    }
    __syncthreads();                               // (8)
    if (tid < 32){
      float y = bl[tid];
      #pragma unroll
      for (int p2 = 0; p2 < 8; p2++) y += pool[p2*32 + tid];
      ylds[tid] = y;
      outp[31 + t*32 + tid] = y;
    }
  }
}

extern "C" void kernel_launch(void* const* d_in, const int* in_sizes, int n_in,
                              void* d_out, int out_size, void* d_ws, size_t ws_size,
                              hipStream_t stream){
  const float* x       = (const float*)d_in[0];
  const int*   lengths = (const int*)  d_in[1];
  const float* dec_h0  = (const float*)d_in[2];
  const float* dec_c0  = (const float*)d_in[3];
  const float* Wih_f   = (const float*)d_in[4];
  const float* Whh_f   = (const float*)d_in[5];
  const float* b_f     = (const float*)d_in[6];
  const float* Wih_b   = (const float*)d_in[7];
  const float* Whh_b   = (const float*)d_in[8];
  const float* b_b     = (const float*)d_in[9];
  const float* Wa      = (const float*)d_in[10];
  const float* ba      = (const float*)d_in[11];
  const float* v       = (const float*)d_in[12];
  const float* Wih_d   = (const float*)d_in[13];
  const float* Whh_d   = (const float*)d_in[14];
  const float* b_d     = (const float*)d_in[15];
  const float* Wl      = (const float*)d_in[16];
  const float* bl      = (const float*)d_in[17];
  float* ws  = (float*)d_ws;
  float* out = (float*)d_out;

  pack_kernel<<<1776, 256, 0, stream>>>(Whh_f, Whh_b, Wih_f, Wih_b, Whh_d, Wa, Wih_d, Wl, ws);
  zc_kernel<<<32, 512, 0, stream>>>(dec_h0, b_d, ws);
  xw_kernel<<<1024, 512, 0, stream>>>(x, lengths, b_f, b_b, ws);
  lstm_kernel<<<64, 512, 0, stream>>>(lengths, ws);
  proj_kernel<<<512, 192, 0, stream>>>(lengths, ba, ws);
  decoder_kernel<<<32, 512, 0, stream>>>(lengths, dec_h0, dec_c0, v, bl, ws, out);
}

// Round 4
// 2856.335 us; speedup vs baseline: 1.0296x; 1.0296x over previous
//
#include <hip/hip_runtime.h>

#define BB 32
#define TT 256
#define INP 64
#define EE 128
#define DD 128
#define OO 32

// ---- workspace layout (float offsets) ----
// ENCWH aliases XWF; EPT/ENCWLH alias XWB (stream-ordered: xw -> lstm consumes XW,
// then proj writes EPT/ENCWH/ENCWLH, then decoder reads them).
#define OFF_XWF    0u          // B*T*512 staging (xw -> lstm)
#define OFF_ENCWH  0u          // B*128*512 half2-as-float (proj -> decoder)
#define OFF_XWB    4194304u    // B*T*512 staging
#define OFF_EPT    4194304u    // B*256*128 fp32, t-major, pre-scaled by 2*log2e
#define OFF_ENCWLH 5242880u    // B*128*32 half2-as-float
#define OFF_HF     8388608u    // B*T*128
#define OFF_HBR    9437184u    // B*T*128
#define OFF_ZC     10485760u   // B*512
#define OFF_WHHTF  10502144u   // 512*128 packed [k4][j][4]
#define OFF_WHHTB  10567680u
#define OFF_WIHTF  10633216u   // 512*64  packed [i4][j][4]
#define OFF_WIHTB  10665984u
#define OFF_WHHDT  10698752u   // 512*128 packed [k4][j][4]
#define OFF_WCAT   10764288u   // 256*672 packed [k4][j][4]
#define OFF_WLHT   10936320u   // 128*32 packed [k4][m][4] fp32
#define OFF_WAHH   10940416u   // 128*64 half2 [d][k2]
#define OFF_WYH    10948608u   // 16*512 half2 [m2][j]

typedef _Float16 h2_t __attribute__((ext_vector_type(2)));
typedef _Float16 half8_t __attribute__((ext_vector_type(8)));
typedef float f32x4_t __attribute__((ext_vector_type(4)));

__device__ __forceinline__ float fexp2(float x){ return __builtin_amdgcn_exp2f(x); }
__device__ __forceinline__ float frcp(float x){ return __builtin_amdgcn_rcpf(x); }
__device__ __forceinline__ float fsig(float x){ return frcp(1.0f + fexp2(-1.4426950408889634f * x)); }
__device__ __forceinline__ float ftanh_(float x){ return 1.0f - 2.0f * frcp(1.0f + fexp2(2.8853900817779268f * x)); }
__device__ __forceinline__ float packh2(float a, float b){
  h2_t t; t.x = (_Float16)a; t.y = (_Float16)b; return __builtin_bit_cast(float, t);
}
__device__ __forceinline__ h2_t ash2(float f){ return __builtin_bit_cast(h2_t, f); }
__device__ __forceinline__ float fdot2_(float a, float b, float c){
  return __builtin_amdgcn_fdot2(ash2(a), ash2(b), c, false);
}

#define C2F 2.8853900817779268f
#define L2E 1.4426950408889634f

// PIN: make a loaded value opaque to LLVM so it cannot be rematerialized
// (re-loaded) inside the loop. ws is __restrict__/read-only here, so plain
// loads are always legal to sink into the loop -- R1-R3 evidence: VGPR stuck
// at 128 and per-step L2 re-reads regardless of launch bounds / named SSA.
// The asm def breaks the load-derivation chain: the value MUST live in "v".
#define PINV(x) asm volatile("" : "+v"(x))

#define REP4(M)  M(0) M(1) M(2) M(3)
#define REP8(M)  M(0) M(1) M(2) M(3) M(4) M(5) M(6) M(7)
#define REP9(M)  M(0) M(1) M(2) M(3) M(4) M(5) M(6) M(7) M(8)
#define REP16(M) M(0) M(1) M(2) M(3) M(4) M(5) M(6) M(7) M(8) M(9) M(10) M(11) M(12) M(13) M(14) M(15)
#define REP32(M) M(0) M(1) M(2) M(3) M(4) M(5) M(6) M(7) M(8) M(9) M(10) M(11) M(12) M(13) M(14) M(15) \
                 M(16) M(17) M(18) M(19) M(20) M(21) M(22) M(23) M(24) M(25) M(26) M(27) M(28) M(29) M(30) M(31)

// ---------------- K0a: weight transposes / packing ----------------
__global__ void pack_kernel(const float* __restrict__ Whh_f, const float* __restrict__ Whh_b,
                            const float* __restrict__ Wih_f, const float* __restrict__ Wih_b,
                            const float* __restrict__ Whh_d, const float* __restrict__ Wa,
                            const float* __restrict__ Wih_d, const float* __restrict__ Wl,
                            float* __restrict__ ws){
  unsigned e = blockIdx.x * 256u + threadIdx.x;
  if (e < 65536u){ unsigned j=e>>7, k=e&127u; ws[OFF_WHHTF + (k>>2)*2048u + j*4u + (k&3u)] = Whh_f[e]; return; }
  e -= 65536u;
  if (e < 65536u){ unsigned j=e>>7, k=e&127u; ws[OFF_WHHTB + (k>>2)*2048u + j*4u + (k&3u)] = Whh_b[e]; return; }
  e -= 65536u;
  if (e < 32768u){ unsigned j=e>>6, i=e&63u; ws[OFF_WIHTF + (i>>2)*2048u + j*4u + (i&3u)] = Wih_f[e]; return; }
  e -= 32768u;
  if (e < 32768u){ unsigned j=e>>6, i=e&63u; ws[OFF_WIHTB + (i>>2)*2048u + j*4u + (i&3u)] = Wih_b[e]; return; }
  e -= 32768u;
  if (e < 65536u){ unsigned j=e>>7, k=e&127u; ws[OFF_WHHDT + (k>>2)*2048u + j*4u + (k&3u)] = Whh_d[e]; return; }
  e -= 65536u;
  if (e < 172032u){
    unsigned j = e >> 8, k = e & 255u;  // j<672, k<256
    float val;
    if (j < 128u)      val = Wa[j*384u + 128u + k];
    else if (j < 640u) val = Wih_d[(j-128u)*288u + 32u + k];
    else               val = Wl[(j-640u)*384u + 128u + k];
    ws[OFF_WCAT + (k>>2)*2688u + j*4u + (k&3u)] = val; return;
  }
  e -= 172032u;
  if (e < 4096u){ unsigned k=e>>5, m=e&31u; ws[OFF_WLHT + (k>>2)*128u + m*4u + (k&3u)] = Wl[m*384u + k]; return; }
  e -= 4096u;
  if (e < 8192u){ // WAHH [d][k2] fp16 pairs over k
    unsigned d = e >> 6, k2 = e & 63u;
    ws[OFF_WAHH + e] = packh2(Wa[d*384u + 2u*k2], Wa[d*384u + 2u*k2 + 1u]); return;
  }
  e -= 8192u;
  if (e < 8192u){ // WYH [m2][j] fp16 pairs over m (first 32 cols of Wih_d)
    unsigned m2 = e >> 9, j = e & 511u;
    ws[OFF_WYH + e] = packh2(Wih_d[j*288u + 2u*m2], Wih_d[j*288u + 2u*m2 + 1u]); return;
  }
}

// ---------------- K0b: zc[b][j] = b_d[j] + dec_h0[b] @ Whh_d[j,:] ----------------
__global__ __launch_bounds__(512) void zc_kernel(const float* __restrict__ dec_h0,
                                                 const float* __restrict__ b_d,
                                                 float* __restrict__ ws){
  __shared__ __align__(16) float h0[128];
  int b = blockIdx.x, j = threadIdx.x;
  if (j < 128) h0[j] = dec_h0[b*128 + j];
  __syncthreads();
  const float* WT = ws + OFF_WHHDT;
  float4 a4 = make_float4(0.f,0.f,0.f,0.f);
  #pragma unroll
  for (int k4 = 0; k4 < 32; k4++){
    float4 wv = *(const float4*)(WT + k4*2048 + j*4);
    float4 hv = *(const float4*)(h0 + k4*4);
    a4.x += wv.x*hv.x; a4.y += wv.y*hv.y; a4.z += wv.z*hv.z; a4.w += wv.w*hv.w;
  }
  ws[OFF_ZC + b*512 + j] = b_d[j] + (a4.x + a4.y) + (a4.z + a4.w);
}

// ---------------- K1: xW staging ----------------
__global__ __launch_bounds__(512) void xw_kernel(const float* __restrict__ x,
                                                 const int* __restrict__ lengths,
                                                 const float* __restrict__ b_f,
                                                 const float* __restrict__ b_b,
                                                 float* __restrict__ ws){
  int bx = blockIdx.x;
  int dir = bx >> 9, b = (bx >> 4) & 31, tile = bx & 15;
  int t0 = tile * 16;
  int len = lengths[b];
  __shared__ __align__(16) float xrow[16][64];
  const float* WT   = ws + (dir ? OFF_WIHTB : OFF_WIHTF);
  const float* bias = dir ? b_b : b_f;
  float* out = ws + (dir ? OFF_XWB : OFF_XWF) + (unsigned)b * TT * 512;
  int tid = threadIdx.x;
  for (int idx = tid; idx < 1024; idx += 512){
    int r = idx >> 6, i = idx & 63;
    int s = t0 + r;
    int src = dir ? ((s < len) ? (len - 1 - s) : 0) : s;
    xrow[r][i] = x[((unsigned)b * TT + src) * 64 + i];
  }
  __syncthreads();
  int j = tid;
  float bj = bias[j];
  float acc[16];
  #pragma unroll
  for (int r = 0; r < 16; r++) acc[r] = bj;
  #pragma unroll 4
  for (int i4 = 0; i4 < 16; i4++){
    float4 wv = *(const float4*)(WT + i4*2048 + j*4);
    #pragma unroll
    for (int r = 0; r < 16; r++){
      float4 xv = *(const float4*)(&xrow[r][i4*4]);
      acc[r] += wv.x*xv.x + wv.y*xv.y + wv.z*xv.z + wv.w*xv.w;
    }
  }
  #pragma unroll
  for (int r = 0; r < 16; r++) out[(t0 + r)*512 + j] = acc[r];
}

// ---------------- K2: LSTM recurrence ----------------
// Whh row in 32 PINNED f32x4 registers: asm-opaque so the loop cannot
// re-load them from global each step (remat). 64 blocks -> 1/CU.
__global__ __launch_bounds__(512) __attribute__((amdgpu_waves_per_eu(2, 2)))
void lstm_kernel(const int* __restrict__ lengths,
                 float* __restrict__ ws){
  int bx = blockIdx.x;
  int b = bx & 31, dir = bx >> 5;
  int len = lengths[b];
  if (len < 1) len = 1; if (len > TT) len = TT;
  const float* xW = ws + (dir ? OFF_XWB : OFF_XWF) + (unsigned)b * TT * 512;
  const float* WT = ws + (dir ? OFF_WHHTB : OFF_WHHTF);
  float* hout = ws + (dir ? OFF_HBR : OFF_HF) + (unsigned)b * TT * 128;
  __shared__ __align__(16) float hsh[128];
  __shared__ __align__(16) float csh[128];
  __shared__ __align__(16) float zsh[512];
  int j = threadIdx.x;
#define DECLW(i) f32x4_t w##i = *(const f32x4_t*)(WT + (i)*2048 + j*4); PINV(w##i);
  REP32(DECLW)
#undef DECLW
  if (j < 128){ hsh[j] = 0.f; csh[j] = 0.f; }
  for (int t = 0; t < len; t++){
    __syncthreads();
    float ax = xW[t*512 + j], ay = 0.f, az = 0.f, aw = 0.f;
#define ACCW(i) { f32x4_t hv = *(const f32x4_t*)(hsh + (i)*4); \
    ax = fmaf(w##i.x, hv.x, ax); ay = fmaf(w##i.y, hv.y, ay); \
    az = fmaf(w##i.z, hv.z, az); aw = fmaf(w##i.w, hv.w, aw); }
    REP32(ACCW)
#undef ACCW
    zsh[j] = (ax + ay) + (az + aw);
    __syncthreads();
    if (j < 128){
      float zi = zsh[j], zf = zsh[128+j], zg = zsh[256+j], zo = zsh[384+j];
      float c = fsig(zf)*csh[j] + fsig(zi)*ftanh_(zg);
      float h = fsig(zo)*ftanh_(c);
      csh[j] = c; hsh[j] = h;
      hout[t*128 + j] = h;
    }
  }
}

// ---------------- K3: enc projections -> EPT (t-major fp32), ENCWH/ENCWLH (fp16 pairs) ----------------
__global__ __launch_bounds__(192) void proj_kernel(const int* __restrict__ lengths,
                                                   const float* __restrict__ ba,
                                                   float* __restrict__ ws){
  int bx = blockIdx.x;
  int b = bx >> 4, tile = bx & 15;
  int len = lengths[b];
  if (len < 1) len = 1; if (len > TT) len = TT;
  int t0 = tile * 16;
  __shared__ __align__(16) float enc[16][256];
  int tid = threadIdx.x;
  const float* hf  = ws + OFF_HF  + (unsigned)b * TT * 128;
  const float* hbr = ws + OFF_HBR + (unsigned)b * TT * 128;
  for (int idx = tid; idx < 4096; idx += 192){
    int r = idx >> 8, k = idx & 255;
    int t = t0 + r;
    float vv = 0.f;
    if (t < len) vv = (k < 128) ? hf[t*128 + k] : hbr[(len-1-t)*128 + (k-128)];
    enc[r][k] = vv;
  }
  __syncthreads();
  if (tid >= 168) return;
  int j0 = tid * 4;
  float acc[16][4];
  #pragma unroll
  for (int r = 0; r < 16; r++){ acc[r][0]=0.f; acc[r][1]=0.f; acc[r][2]=0.f; acc[r][3]=0.f; }
  const float* WC = ws + OFF_WCAT;
  for (int k4 = 0; k4 < 64; k4++){
    float4 w0 = *(const float4*)(WC + k4*2688 + (j0+0)*4);
    float4 w1 = *(const float4*)(WC + k4*2688 + (j0+1)*4);
    float4 w2 = *(const float4*)(WC + k4*2688 + (j0+2)*4);
    float4 w3 = *(const float4*)(WC + k4*2688 + (j0+3)*4);
    #pragma unroll
    for (int r = 0; r < 16; r++){
      float4 ev = *(const float4*)(&enc[r][k4*4]);
      acc[r][0] += w0.x*ev.x + w0.y*ev.y + w0.z*ev.z + w0.w*ev.w;
      acc[r][1] += w1.x*ev.x + w1.y*ev.y + w1.z*ev.z + w1.w*ev.w;
      acc[r][2] += w2.x*ev.x + w2.y*ev.y + w2.z*ev.z + w2.w*ev.w;
      acc[r][3] += w3.x*ev.x + w3.y*ev.y + w3.z*ev.z + w3.w*ev.w;
    }
  }
  float* epo  = ws + OFF_EPT    + (unsigned)b * TT * 128;   // [t][d]
  float* eWh  = ws + OFF_ENCWH  + (unsigned)b * 128 * 512;  // [t2][j] half2
  float* eWlh = ws + OFF_ENCWLH + (unsigned)b * 128 * 32;   // [t2][m] half2
  #pragma unroll
  for (int c = 0; c < 4; c++){
    int j = j0 + c;
    if (j < 128){
      float bj = ba[j];
      for (int r = 0; r < 16; r++) epo[(t0 + r)*128 + j] = (acc[r][c] + bj) * C2F;
    } else if (j < 640){
      for (int r2 = 0; r2 < 8; r2++)
        eWh[(tile*8 + r2)*512 + (j - 128)] = packh2(acc[2*r2][c], acc[2*r2+1][c]);
    } else {
      for (int r2 = 0; r2 < 8; r2++)
        eWlh[(tile*8 + r2)*32 + (j - 640)] = packh2(acc[2*r2][c], acc[2*r2+1][c]);
    }
  }
}

// ---------------- K4: attention decoder ----------------
// MFMA edition, PINNED-register build: the 36 Phase-D B-fragments + 4 Phase-A
// fragments (+zc, v) are forced into arch VGPRs via empty-asm defs, so LLVM
// cannot sink their global loads into the t-loop (the R1-R3 failure mode:
// per-step L2 gather with 2 waves/SIMD = latency-bound Phase D).
__global__ __launch_bounds__(512) __attribute__((amdgpu_waves_per_eu(2, 2)))
void decoder_kernel(const int* __restrict__ lengths,
                    const float* __restrict__ dec_h0,
                    const float* __restrict__ dec_c0,
                    const float* __restrict__ v,
                    const float* __restrict__ bl,
                    float* __restrict__ ws,
                    float* __restrict__ out){
  __shared__ __align__(16) float ep_lds[32768];   // [t][d] linear, fp32
  __shared__ __align__(16) float pool[4096];      // partial / zsh / red (disjoint live ranges)
  __shared__ __align__(16) float qsh[128];        // C2F * q_d
  __shared__ __align__(16) float au_h2[144];      // half2 pairs: a over t [0..127], y over m [128..143]
  __shared__ __align__(16) float hsh[128];
  __shared__ __align__(16) float c0sh[128];
  __shared__ __align__(16) float h_h2[64];        // half2 pairs of h over k
  __shared__ __align__(16) float ylds[32];
  __shared__ float mlsw[8];                       // per-wave {max, sum} pairs

  int b = blockIdx.x;
  int len = lengths[b];
  if (len < 1) len = 1; if (len > TT) len = TT;
  int tid = threadIdx.x;
  int lane = tid & 63, w = tid >> 6;
  int rg = lane >> 4, c16 = lane & 15;
  int rg4 = rg * 4;
  int dg = tid & 31, tg = tid >> 5;
  int dg4 = dg * 4;

  const float* EPT  = ws + OFF_EPT    + (unsigned)b * 32768;
  const float* EWH  = ws + OFF_ENCWH  + (unsigned)b * 65536;
  const float* EWLH = ws + OFF_ENCWLH + (unsigned)b * 4096;
  const float* WLHT = ws + OFF_WLHT;
  float* outp = out + (unsigned)b * 8223;

  // ---- persistent B fragments for Phase D: [encW(256); Wy(32)] f16, 64 cols per wave ----
  // layout per MFMA 16x16x32: lane holds B[k = ks*32 + (lane>>4)*8 + c][col = w*64+nt*16+(lane&15)]
  half8_t bf0_0, bf0_1, bf0_2, bf0_3, bf0_4, bf0_5, bf0_6, bf0_7, bf0_8;
  half8_t bf1_0, bf1_1, bf1_2, bf1_3, bf1_4, bf1_5, bf1_6, bf1_7, bf1_8;
  half8_t bf2_0, bf2_1, bf2_2, bf2_3, bf2_4, bf2_5, bf2_6, bf2_7, bf2_8;
  half8_t bf3_0, bf3_1, bf3_2, bf3_3, bf3_4, bf3_5, bf3_6, bf3_7, bf3_8;
  int j0_ = w*64 + 0*16 + c16;
  int j1_ = w*64 + 1*16 + c16;
  int j2_ = w*64 + 2*16 + c16;
  int j3_ = w*64 + 3*16 + c16;
#define LDBF(nt, ks) { float4 t_; \
    t_.x = EWH[((ks)*16 + rg4 + 0)*512 + j##nt##_]; \
    t_.y = EWH[((ks)*16 + rg4 + 1)*512 + j##nt##_]; \
    t_.z = EWH[((ks)*16 + rg4 + 2)*512 + j##nt##_]; \
    t_.w = EWH[((ks)*16 + rg4 + 3)*512 + j##nt##_]; \
    bf##nt##_##ks = __builtin_bit_cast(half8_t, t_); PINV(bf##nt##_##ks); }
#define LDBF0(ks) LDBF(0, ks)
#define LDBF1(ks) LDBF(1, ks)
#define LDBF2(ks) LDBF(2, ks)
#define LDBF3(ks) LDBF(3, ks)
  REP8(LDBF0) REP8(LDBF1) REP8(LDBF2) REP8(LDBF3)
#undef LDBF0
#undef LDBF1
#undef LDBF2
#undef LDBF3
#undef LDBF
  // ks = 8 slot is Wy:
  {
#define LDBY(nt) { float4 t_; \
    t_.x = ws[OFF_WYH + (rg4 + 0)*512 + j##nt##_]; \
    t_.y = ws[OFF_WYH + (rg4 + 1)*512 + j##nt##_]; \
    t_.z = ws[OFF_WYH + (rg4 + 2)*512 + j##nt##_]; \
    t_.w = ws[OFF_WYH + (rg4 + 3)*512 + j##nt##_]; \
    bf##nt##_8 = __builtin_bit_cast(half8_t, t_); PINV(bf##nt##_8); }
    LDBY(0) LDBY(1) LDBY(2) LDBY(3)
#undef LDBY
  }
  // ---- persistent B fragments for Phase A: Wa_h f16, 16 q-outputs per wave ----
  half8_t wa0, wa1, wa2, wa3;
  {
    int dq = w*16 + c16;
#define LDWA(ks) { float4 t_; \
    t_.x = ws[OFF_WAHH + dq*64 + (ks)*16 + rg4 + 0]; \
    t_.y = ws[OFF_WAHH + dq*64 + (ks)*16 + rg4 + 1]; \
    t_.z = ws[OFF_WAHH + dq*64 + (ks)*16 + rg4 + 2]; \
    t_.w = ws[OFF_WAHH + dq*64 + (ks)*16 + rg4 + 3]; \
    wa##ks = __builtin_bit_cast(half8_t, t_); PINV(wa##ks); }
    REP4(LDWA)
#undef LDWA
  }
  float zc_0 = ws[OFF_ZC + b*512 + w*64 +  0 + c16]; PINV(zc_0);
  float zc_1 = ws[OFF_ZC + b*512 + w*64 + 16 + c16]; PINV(zc_1);
  float zc_2 = ws[OFF_ZC + b*512 + w*64 + 32 + c16]; PINV(zc_2);
  float zc_3 = ws[OFF_ZC + b*512 + w*64 + 48 + c16]; PINV(zc_3);
  float vx = v[dg4 + 0], vy = v[dg4 + 1], vz = v[dg4 + 2], vw = v[dg4 + 3];
  PINV(vx); PINV(vy); PINV(vz); PINV(vw);

  // ---- ep -> LDS (linear, vectorized) ----
  {
    const float4* src = (const float4*)EPT;
    float4* dst = (float4*)ep_lds;
    #pragma unroll
    for (int c = 0; c < 16; c++) dst[c*512 + tid] = src[c*512 + tid];
  }
  if (tid < 128){
    hsh[tid]  = dec_h0[b*128 + tid];
    c0sh[tid] = dec_c0[b*128 + tid];
  }
  if (tid < 64) h_h2[tid] = packh2(dec_h0[b*128 + 2*tid], dec_h0[b*128 + 2*tid + 1]);
  if (tid < 32) ylds[tid] = 0.f;
  if (tid < 31) outp[tid] = 0.f;

  for (int t = 0; t < TT; t++){
    __syncthreads();                               // (1) ylds/h_h2 ready
    if (tid < 16) au_h2[128 + tid] = packh2(ylds[2*tid], ylds[2*tid+1]);
    // ---- Phase A: q = Wa_h.h via MFMA (A rows replicated with h) ----
    {
      f32x4_t qa = {0.f, 0.f, 0.f, 0.f};
#define MFA(ks) { float4 hf4_ = *(const float4*)(h_h2 + (ks)*16 + rg4); \
      qa = __builtin_amdgcn_mfma_f32_16x16x32_f16(__builtin_bit_cast(half8_t, hf4_), wa##ks, qa, 0, 0, 0); }
      REP4(MFA)
#undef MFA
      if (rg == 0) qsh[w*16 + c16] = qa[0] * C2F;
    }
    __syncthreads();                               // (2) qsh ready
    // ---- Phase B: per-thread 4d x 16t sigmoid-dot partials (named p0..p15) ----
    {
      float4 q4 = *(const float4*)(qsh + dg4);
      int t0 = tg * 16;
#define PBC(k) float p##k = 0.f; \
      if (t0 + (k) < len){ \
        float4 e4_ = *(const float4*)(ep_lds + (t0 + (k))*128 + dg4); \
        p##k =      vx * frcp(1.f + fexp2(e4_.x + q4.x)); \
        p##k = fmaf(vy, frcp(1.f + fexp2(e4_.y + q4.y)), p##k); \
        p##k = fmaf(vz, frcp(1.f + fexp2(e4_.z + q4.z)), p##k); \
        p##k = fmaf(vw, frcp(1.f + fexp2(e4_.w + q4.w)), p##k); \
      } \
      p##k += __shfl_xor(p##k, 16);
      REP16(PBC)
#undef PBC
      if (dg < 16){
#define STP(k) pool[dg*256 + ((t0 + (k) + dg) & 255)] = p##k;
        REP16(STP)
#undef STP
      }
    }
    __syncthreads();                               // (3) partials ready
    // ---- Phase C: softmax (one cross-wave exchange) ----
    float e = 0.f, mm = -1e30f;
    if (tid < 256){
      float s = -1e30f;
      if (tid < len){
        float ps = 0.f;
        #pragma unroll
        for (int dgi = 0; dgi < 16; dgi++)
          ps += pool[dgi*256 + ((tid + dgi) & 255)];
        s = ps * (-2.f * L2E);                     // vsum constant cancels in softmax
      }
      mm = s;
      #pragma unroll
      for (int off = 32; off; off >>= 1) mm = fmaxf(mm, __shfl_xor(mm, off));
      if (tid < len) e = fexp2(s - mm);
      float ss = e;
      #pragma unroll
      for (int off = 32; off; off >>= 1) ss += __shfl_xor(ss, off);
      if ((tid & 63) == 0){ mlsw[(tid>>6)*2] = mm; mlsw[(tid>>6)*2 + 1] = ss; }
    }
    __syncthreads();                               // (4) wave max/sum ready
    if (tid < 256){
      float gm = fmaxf(fmaxf(mlsw[0], mlsw[2]), fmaxf(mlsw[4], mlsw[6]));
      float tot = mlsw[1]*fexp2(mlsw[0] - gm) + mlsw[3]*fexp2(mlsw[2] - gm)
                + mlsw[5]*fexp2(mlsw[4] - gm) + mlsw[7]*fexp2(mlsw[6] - gm);
      float scale = fexp2(mm - gm) * frcp(tot);
      float e1 = __shfl_xor(e, 1);
      if (!(tid & 1)) au_h2[tid >> 1] = packh2(e*scale, e1*scale);
    }
    __syncthreads();                               // (5) a ready
    // ---- Phase D: z = zc + [a;y].[encW;Wy] via MFMA (A rows replicated) ----
    {
      f32x4_t a0 = {zc_0, zc_0, zc_0, zc_0};
      f32x4_t a1 = {zc_1, zc_1, zc_1, zc_1};
      f32x4_t a2 = {zc_2, zc_2, zc_2, zc_2};
      f32x4_t a3 = {zc_3, zc_3, zc_3, zc_3};
#define MFD(ks) { float4 af_ = *(const float4*)(au_h2 + (ks)*16 + rg4); \
      half8_t a8_ = __builtin_bit_cast(half8_t, af_); \
      a0 = __builtin_amdgcn_mfma_f32_16x16x32_f16(a8_, bf0_##ks, a0, 0, 0, 0); \
      a1 = __builtin_amdgcn_mfma_f32_16x16x32_f16(a8_, bf1_##ks, a1, 0, 0, 0); \
      a2 = __builtin_amdgcn_mfma_f32_16x16x32_f16(a8_, bf2_##ks, a2, 0, 0, 0); \
      a3 = __builtin_amdgcn_mfma_f32_16x16x32_f16(a8_, bf3_##ks, a3, 0, 0, 0); }
      REP9(MFD)
#undef MFD
      float zv = (rg == 0) ? a0[0] : (rg == 1) ? a1[0] : (rg == 2) ? a2[0] : a3[0];
      pool[tid] = zv;                              // zsh alias; j == tid mapping preserved
    }
    __syncthreads();                               // (6) z ready
    // ---- Phase E: gates (c0 constant per reference) ----
    if (tid < 128){
      float zi = pool[tid], zf = pool[128+tid], zg = pool[256+tid], zo = pool[384+tid];
      float c = fsig(zf)*c0sh[tid] + fsig(zi)*ftanh_(zg);
      hsh[tid] = fsig(zo)*ftanh_(c);
    }
    __syncthreads();                               // (7) h ready
    // pack h to half2 (idle lanes), in parallel with Phase F
    if (tid >= 256 && tid < 320){
      int i = tid - 256;
      h_h2[i] = packh2(hsh[2*i], hsh[2*i+1]);
    }
    // ---- Phase F: y = a.eWl + h.Wl_h + bl ----
    if (tid < 256){
      int m = tid & 31, pp = tid >> 5;
      float acc = 0.f;
      #pragma unroll
      for (int ri = 0; ri < 16; ri++){
        int r = pp + ri*8;
        acc = fdot2_(au_h2[r], EWLH[r*32 + m], acc);
      }
      #pragma unroll
      for (int k4 = pp; k4 < 32; k4 += 8){
        float4 hv = *(const float4*)(hsh + k4*4);
        float4 wv = *(const float4*)(WLHT + k4*128 + m*4);
        acc += hv.x*wv.x + hv.y*wv.y + hv.z*wv.z + hv.w*wv.w;
      }
      pool[tid] = acc;                             // red alias (256 entries)
    }
    __syncthreads();                               // (8)
    if (tid < 32){
      float y = bl[tid];
      #pragma unroll
      for (int p2 = 0; p2 < 8; p2++) y += pool[p2*32 + tid];
      ylds[tid] = y;
      outp[31 + t*32 + tid] = y;
    }
  }
}

extern "C" void kernel_launch(void* const* d_in, const int* in_sizes, int n_in,
                              void* d_out, int out_size, void* d_ws, size_t ws_size,
                              hipStream_t stream){
  const float* x       = (const float*)d_in[0];
  const int*   lengths = (const int*)  d_in[1];
  const float* dec_h0  = (const float*)d_in[2];
  const float* dec_c0  = (const float*)d_in[3];
  const float* Wih_f   = (const float*)d_in[4];
  const float* Whh_f   = (const float*)d_in[5];
  const float* b_f     = (const float*)d_in[6];
  const float* Wih_b   = (const float*)d_in[7];
  const float* Whh_b   = (const float*)d_in[8];
  const float* b_b     = (const float*)d_in[9];
  const float* Wa      = (const float*)d_in[10];
  const float* ba      = (const float*)d_in[11];
  const float* v       = (const float*)d_in[12];
  const float* Wih_d   = (const float*)d_in[13];
  const float* Whh_d   = (const float*)d_in[14];
  const float* b_d     = (const float*)d_in[15];
  const float* Wl      = (const float*)d_in[16];
  const float* bl      = (const float*)d_in[17];
  float* ws  = (float*)d_ws;
  float* out = (float*)d_out;

  pack_kernel<<<1776, 256, 0, stream>>>(Whh_f, Whh_b, Wih_f, Wih_b, Whh_d, Wa, Wih_d, Wl, ws);
  zc_kernel<<<32, 512, 0, stream>>>(dec_h0, b_d, ws);
  xw_kernel<<<1024, 512, 0, stream>>>(x, lengths, b_f, b_b, ws);
  lstm_kernel<<<64, 512, 0, stream>>>(lengths, ws);
  proj_kernel<<<512, 192, 0, stream>>>(lengths, ba, ws);
  decoder_kernel<<<32, 512, 0, stream>>>(lengths, dec_h0, dec_c0, v, bl, ws, out);
}